// Round 1
// baseline (384.124 us; speedup 1.0000x reference)
//
#include <hip/hip_runtime.h>
#include <math.h>

#define F 256
#define NROW 128
#define EPS 1e-12f

// ---------------- K0: cn = l2norm(cell) rows ----------------
__global__ __launch_bounds__(256) void l2norm_rows(const float* __restrict__ x,
                                                   float* __restrict__ out,
                                                   int nrows) {
    int wave = blockIdx.x * 4 + (threadIdx.x >> 6);
    int lane = threadIdx.x & 63;
    if (wave >= nrows) return;
    const float4* xr = (const float4*)(x + (size_t)wave * F);
    float4 v = xr[lane];
    float s = v.x * v.x + v.y * v.y + v.z * v.z + v.w * v.w;
#pragma unroll
    for (int m = 1; m < 64; m <<= 1) s += __shfl_xor(s, m, 64);
    float inv = 1.0f / fmaxf(sqrtf(s), EPS);
    float4 o = {v.x * inv, v.y * inv, v.z * inv, v.w * inv};
    ((float4*)(out + (size_t)wave * F))[lane] = o;
}

// ---------------- K1: M[f,g] = q_row_f . k_row_g  (M = q @ k^T) ----------------
__global__ __launch_bounds__(256) void qkT_kernel(const float* __restrict__ q,
                                                  const float* __restrict__ k,
                                                  float* __restrict__ M) {
    __shared__ float qs[F];
    int f = blockIdx.x;
    qs[threadIdx.x] = q[(size_t)f * F + threadIdx.x];
    __syncthreads();
    int g = threadIdx.x;
    const float4* kr = (const float4*)(k + (size_t)g * F);
    const float4* qr = (const float4*)qs;
    float acc = 0.f;
#pragma unroll 8
    for (int j = 0; j < F / 4; j++) {
        float4 kv = kr[j];
        float4 qv = qr[j];
        acc += kv.x * qv.x + kv.y * qv.y + kv.z * qv.z + kv.w * qv.w;
    }
    M[(size_t)f * F + g] = acc;
}

// ---------------- K2: W = CN @ M  (tiled fp32 GEMM, 32x64 tile) ----------------
__global__ __launch_bounds__(256) void w_gemm(const float* __restrict__ CN,
                                              const float* __restrict__ M,
                                              float* __restrict__ W) {
    __shared__ float As[32][64];  // [row][k]
    __shared__ float Bs[64][64];  // [k][col]
    int rb = blockIdx.x * 32;
    int cb = blockIdx.y * 64;
    int tid = threadIdx.x;
    int colq = tid & 15;  // 4 cols each
    int rowp = tid >> 4;  // 2 rows each
    float acc[2][4] = {{0.f, 0.f, 0.f, 0.f}, {0.f, 0.f, 0.f, 0.f}};
    for (int k0 = 0; k0 < F; k0 += 64) {
        __syncthreads();
#pragma unroll
        for (int e = 0; e < 2; e++) {
            int s = tid + e * 256;
            int r = s >> 4;
            int c = (s & 15) << 2;
            *(float4*)&As[r][c] = *(const float4*)&CN[(size_t)(rb + r) * F + k0 + c];
        }
#pragma unroll
        for (int e = 0; e < 4; e++) {
            int s = tid + e * 256;
            int r = s >> 4;
            int c = (s & 15) << 2;
            *(float4*)&Bs[r][c] = *(const float4*)&M[(size_t)(k0 + r) * F + cb + c];
        }
        __syncthreads();
#pragma unroll
        for (int kk = 0; kk < 64; kk++) {
            float4 b4 = *(const float4*)&Bs[kk][colq * 4];
            float a0 = As[rowp * 2 + 0][kk];
            float a1 = As[rowp * 2 + 1][kk];
            acc[0][0] += a0 * b4.x; acc[0][1] += a0 * b4.y;
            acc[0][2] += a0 * b4.z; acc[0][3] += a0 * b4.w;
            acc[1][0] += a1 * b4.x; acc[1][1] += a1 * b4.y;
            acc[1][2] += a1 * b4.z; acc[1][3] += a1 * b4.w;
        }
    }
#pragma unroll
    for (int r = 0; r < 2; r++) {
        float4 o = {acc[r][0], acc[r][1], acc[r][2], acc[r][3]};
        *(float4*)&W[(size_t)(rb + rowp * 2 + r) * F + cb + colq * 4] = o;
    }
}

// ---------------- K3: fused main ----------------
// per block b: for each n: norm2 = |drug[b,n]|^2, aw = w[b].drug, ac = cn[b].drug
// scores[n] = aw/norm, sim[n] = ac/norm; out = softmax(scores)*sim
__global__ __launch_bounds__(256) void fused_main(const float* __restrict__ drug,
                                                  const float* __restrict__ CN,
                                                  const float* __restrict__ W,
                                                  float* __restrict__ out) {
    int b = blockIdx.x;
    int tid = threadIdx.x;
    int wave = tid >> 6;
    int lane = tid & 63;
    int grp = lane >> 4;   // 4 row-groups per wave
    int l16 = lane & 15;   // 16 lanes per row

    __shared__ float sc[NROW];
    __shared__ float sm[NROW];
    __shared__ float red[4];

    // preload per-lane fragments of w and cn: lane covers f = j*64 + l16*4 .. +3
    const float* wrow = W + (size_t)b * F;
    const float* crow = CN + (size_t)b * F;
    float4 w4[4], c4[4];
#pragma unroll
    for (int j = 0; j < 4; j++) {
        w4[j] = *(const float4*)&wrow[j * 64 + l16 * 4];
        c4[j] = *(const float4*)&crow[j * 64 + l16 * 4];
    }

    const float* dbase = drug + (size_t)b * NROW * F;
    // each wave handles 32 rows: 8 iterations x 4 groups
#pragma unroll 2
    for (int it = 0; it < 8; it++) {
        int n = wave * 32 + it * 4 + grp;
        const float* drow = dbase + (size_t)n * F;
        float an = 0.f, aw = 0.f, ac = 0.f;
#pragma unroll
        for (int j = 0; j < 4; j++) {
            float4 v = *(const float4*)&drow[j * 64 + l16 * 4];
            an += v.x * v.x + v.y * v.y + v.z * v.z + v.w * v.w;
            aw += v.x * w4[j].x + v.y * w4[j].y + v.z * w4[j].z + v.w * w4[j].w;
            ac += v.x * c4[j].x + v.y * c4[j].y + v.z * c4[j].z + v.w * c4[j].w;
        }
#pragma unroll
        for (int m = 1; m < 16; m <<= 1) {
            an += __shfl_xor(an, m, 64);
            aw += __shfl_xor(aw, m, 64);
            ac += __shfl_xor(ac, m, 64);
        }
        if (l16 == 0) {
            float inv = 1.0f / fmaxf(sqrtf(an), EPS);
            sc[n] = aw * inv;
            sm[n] = ac * inv;
        }
    }
    __syncthreads();

    // block softmax over 128 scores (threads >=128 duplicate for max, zero for sum)
    float s = sc[tid & 127];
    float v = s;
#pragma unroll
    for (int m = 1; m < 64; m <<= 1) v = fmaxf(v, __shfl_xor(v, m, 64));
    if (lane == 0) red[wave] = v;
    __syncthreads();
    float gmax = fmaxf(fmaxf(red[0], red[1]), fmaxf(red[2], red[3]));
    float e = expf(s - gmax);
    float t = (tid < NROW) ? e : 0.f;
#pragma unroll
    for (int m = 1; m < 64; m <<= 1) t += __shfl_xor(t, m, 64);
    __syncthreads();
    if (lane == 0) red[wave] = t;
    __syncthreads();
    float tot = red[0] + red[1] + red[2] + red[3];
    if (tid < NROW) {
        out[(size_t)b * NROW + tid] = (e / tot) * sm[tid & 127];
    }
}

extern "C" void kernel_launch(void* const* d_in, const int* in_sizes, int n_in,
                              void* d_out, int out_size, void* d_ws, size_t ws_size,
                              hipStream_t stream) {
    const float* drug = (const float*)d_in[0];  // [B, N, F]
    const float* cell = (const float*)d_in[1];  // [B, F]
    const float* k = (const float*)d_in[2];     // [F, F]
    const float* q = (const float*)d_in[3];     // [F, F]
    float* out = (float*)d_out;                 // [B, N]

    int B = in_sizes[1] / F;  // 2048

    float* CN = (float*)d_ws;            // B*F
    float* M = CN + (size_t)B * F;       // F*F
    float* W = M + (size_t)F * F;        // B*F

    // K0: cn = l2norm(cell)
    l2norm_rows<<<dim3((B + 3) / 4), dim3(256), 0, stream>>>(cell, CN, B);
    // K1: M = q @ k^T
    qkT_kernel<<<dim3(F), dim3(256), 0, stream>>>(q, k, M);
    // K2: W = CN @ M
    w_gemm<<<dim3(B / 32, F / 64), dim3(256), 0, stream>>>(CN, M, W);
    // K3: fused scores/softmax/output
    fused_main<<<dim3(B), dim3(256), 0, stream>>>(drug, CN, W, out);
}

// Round 3
// 363.640 us; speedup vs baseline: 1.0563x; 1.0563x over previous
//
#include <hip/hip_runtime.h>
#include <math.h>

#define F 256
#define NROW 128
#define EPS 1e-12f

typedef float vf4 __attribute__((ext_vector_type(4)));

// ---------------- K1: M[f,g] = q_row_f . k_row_g  (M = q @ k^T) ----------------
__global__ __launch_bounds__(256) void qkT_kernel(const float* __restrict__ q,
                                                  const float* __restrict__ k,
                                                  float* __restrict__ M) {
    __shared__ float qs[F];
    int f = blockIdx.x;
    qs[threadIdx.x] = q[(size_t)f * F + threadIdx.x];
    __syncthreads();
    int g = threadIdx.x;
    const float4* kr = (const float4*)(k + (size_t)g * F);
    const float4* qr = (const float4*)qs;
    float acc = 0.f;
#pragma unroll 8
    for (int j = 0; j < F / 4; j++) {
        float4 kv = kr[j];
        float4 qv = qr[j];
        acc += kv.x * qv.x + kv.y * qv.y + kv.z * qv.z + kv.w * qv.w;
    }
    M[(size_t)f * F + g] = acc;
}

// ---------------- K2: W = cell @ M  (raw cell, no normalization) ----------------
// 32 rows x 64 cols per block. Wave w owns rows w*8..w*8+7; As reads are
// wave-uniform (LDS broadcast, conflict-free); Bs[kk][lane] is stride-1
// (2-way alias = free). Old layout had an 8-way As bank conflict.
__global__ __launch_bounds__(256) void w_gemm(const float* __restrict__ cell,
                                              const float* __restrict__ M,
                                              float* __restrict__ W) {
    __shared__ float As[32][64];  // [row][k]   8 KB
    __shared__ float Bs[64][64];  // [k][col]  16 KB
    int rb = blockIdx.x * 32;
    int cb = blockIdx.y * 64;
    int tid = threadIdx.x;
    int wave = tid >> 6;
    int lane = tid & 63;
    float acc[8] = {0.f, 0.f, 0.f, 0.f, 0.f, 0.f, 0.f, 0.f};
    for (int k0 = 0; k0 < F; k0 += 64) {
        __syncthreads();
#pragma unroll
        for (int e = 0; e < 2; e++) {
            int s = tid + e * 256;
            int r = s >> 4;
            int c = (s & 15) << 2;
            *(float4*)&As[r][c] = *(const float4*)&cell[(size_t)(rb + r) * F + k0 + c];
        }
#pragma unroll
        for (int e = 0; e < 4; e++) {
            int s = tid + e * 256;
            int r = s >> 4;
            int c = (s & 15) << 2;
            *(float4*)&Bs[r][c] = *(const float4*)&M[(size_t)(k0 + r) * F + cb + c];
        }
        __syncthreads();
#pragma unroll 4
        for (int kk = 0; kk < 64; kk++) {
            float bv = Bs[kk][lane];
#pragma unroll
            for (int r = 0; r < 8; r++) {
                acc[r] += As[wave * 8 + r][kk] * bv;
            }
        }
    }
#pragma unroll
    for (int r = 0; r < 8; r++) {
        W[(size_t)(rb + wave * 8 + r) * F + cb + lane] = acc[r];
    }
}

// ---------------- K3: fused main ----------------
// per block b: invc = 1/max(||cell[b]||,eps) computed redundantly per 16-lane
// group (each group holds the full 256-wide cell row as 4 float4 fragments).
// For each n: an=|drug|^2, aw=Wraw.d, ac=cell.d;
// scores[n] = aw*invc/|d|, sim[n] = ac*invc/|d|; out = softmax(scores)*sim.
__global__ __launch_bounds__(256) void fused_main(const float* __restrict__ drug,
                                                  const float* __restrict__ cell,
                                                  const float* __restrict__ Wraw,
                                                  float* __restrict__ out) {
    int b = blockIdx.x;
    int tid = threadIdx.x;
    int wave = tid >> 6;
    int lane = tid & 63;
    int grp = lane >> 4;   // 4 row-groups per wave
    int l16 = lane & 15;   // 16 lanes per row

    __shared__ float sc[NROW];
    __shared__ float sm[NROW];
    __shared__ float red[4];

    // per-lane fragments of Wraw and raw cell: lane covers f = j*64 + l16*4 .. +3
    const float* wrow = Wraw + (size_t)b * F;
    const float* crow = cell + (size_t)b * F;
    vf4 w4[4], c4[4];
    float cs = 0.f;
#pragma unroll
    for (int j = 0; j < 4; j++) {
        w4[j] = *(const vf4*)&wrow[j * 64 + l16 * 4];
        c4[j] = *(const vf4*)&crow[j * 64 + l16 * 4];
        cs += c4[j].x * c4[j].x + c4[j].y * c4[j].y + c4[j].z * c4[j].z + c4[j].w * c4[j].w;
    }
#pragma unroll
    for (int m = 1; m < 16; m <<= 1) cs += __shfl_xor(cs, m, 64);
    float invc = 1.0f / fmaxf(sqrtf(cs), EPS);

    const float* dbase = drug + (size_t)b * NROW * F;
    // each wave handles 32 rows: 8 iterations x 4 groups
#pragma unroll 2
    for (int it = 0; it < 8; it++) {
        int n = wave * 32 + it * 4 + grp;
        const float* drow = dbase + (size_t)n * F;
        float an = 0.f, aw = 0.f, ac = 0.f;
#pragma unroll
        for (int j = 0; j < 4; j++) {
            vf4 v = __builtin_nontemporal_load((const vf4*)&drow[j * 64 + l16 * 4]);
            an += v.x * v.x + v.y * v.y + v.z * v.z + v.w * v.w;
            aw += v.x * w4[j].x + v.y * w4[j].y + v.z * w4[j].z + v.w * w4[j].w;
            ac += v.x * c4[j].x + v.y * c4[j].y + v.z * c4[j].z + v.w * c4[j].w;
        }
#pragma unroll
        for (int m = 1; m < 16; m <<= 1) {
            an += __shfl_xor(an, m, 64);
            aw += __shfl_xor(aw, m, 64);
            ac += __shfl_xor(ac, m, 64);
        }
        if (l16 == 0) {
            float inv = invc / fmaxf(sqrtf(an), EPS);
            sc[n] = aw * inv;
            sm[n] = ac * inv;
        }
    }
    __syncthreads();

    // block softmax over 128 scores (threads >=128 duplicate for max, zero for sum)
    float s = sc[tid & 127];
    float v = s;
#pragma unroll
    for (int m = 1; m < 64; m <<= 1) v = fmaxf(v, __shfl_xor(v, m, 64));
    if (lane == 0) red[wave] = v;
    __syncthreads();
    float gmax = fmaxf(fmaxf(red[0], red[1]), fmaxf(red[2], red[3]));
    float e = expf(s - gmax);
    float t = (tid < NROW) ? e : 0.f;
#pragma unroll
    for (int m = 1; m < 64; m <<= 1) t += __shfl_xor(t, m, 64);
    __syncthreads();
    if (lane == 0) red[wave] = t;
    __syncthreads();
    float tot = red[0] + red[1] + red[2] + red[3];
    if (tid < NROW) {
        out[(size_t)b * NROW + tid] = (e / tot) * sm[tid & 127];
    }
}

extern "C" void kernel_launch(void* const* d_in, const int* in_sizes, int n_in,
                              void* d_out, int out_size, void* d_ws, size_t ws_size,
                              hipStream_t stream) {
    const float* drug = (const float*)d_in[0];  // [B, N, F]
    const float* cell = (const float*)d_in[1];  // [B, F]
    const float* k = (const float*)d_in[2];     // [F, F]
    const float* q = (const float*)d_in[3];     // [F, F]
    float* out = (float*)d_out;                 // [B, N]

    int B = in_sizes[1] / F;  // 2048

    float* M = (float*)d_ws;            // F*F
    float* W = M + (size_t)F * F;       // B*F

    // K1: M = q @ k^T
    qkT_kernel<<<dim3(F), dim3(256), 0, stream>>>(q, k, M);
    // K2: W = cell @ M (unnormalized)
    w_gemm<<<dim3(B / 32, F / 64), dim3(256), 0, stream>>>(cell, M, W);
    // K3: fused norms/scores/softmax/output
    fused_main<<<dim3(B), dim3(256), 0, stream>>>(drug, cell, W, out);
}

// Round 4
// 363.009 us; speedup vs baseline: 1.0582x; 1.0017x over previous
//
#include <hip/hip_runtime.h>
#include <math.h>

#define F 256
#define NROW 128
#define EPS 1e-12f

typedef float vf4 __attribute__((ext_vector_type(4)));

// ---------------- K1: M[f,g] = q_row_f . k_row_g  (M = q @ k^T) ----------------
__global__ __launch_bounds__(256) void qkT_kernel(const float* __restrict__ q,
                                                  const float* __restrict__ k,
                                                  float* __restrict__ M) {
    __shared__ float qs[F];
    int f = blockIdx.x;
    qs[threadIdx.x] = q[(size_t)f * F + threadIdx.x];
    __syncthreads();
    int g = threadIdx.x;
    const float4* kr = (const float4*)(k + (size_t)g * F);
    const float4* qr = (const float4*)qs;
    float acc = 0.f;
#pragma unroll 8
    for (int j = 0; j < F / 4; j++) {
        float4 kv = kr[j];
        float4 qv = qr[j];
        acc += kv.x * qv.x + kv.y * qv.y + kv.z * qv.z + kv.w * qv.w;
    }
    M[(size_t)f * F + g] = acc;
}

// ---------------- K3: fused main (now includes w = cell @ M prologue) --------
// Phase 1: w[b] = cell[b] @ M. M (256 KB) is L2-resident (read by all 2048
//   blocks). Thread (fp=wave, c=lane) accumulates cols 4c..4c+3 over f in
//   fp*64..fp*64+63: coalesced b128 M loads, cell[b][f] is block-uniform ->
//   scalar loads. 4 partials reduced through LDS.
// Phase 2: per row n: an=|d|^2, aw=w.d, ac=cell.d; score=aw*invc/|d|,
//   sim=ac*invc/|d|; out = softmax(score)*sim. Drug streamed nontemporal.
__global__ __launch_bounds__(256) void fused_main(const float* __restrict__ drug,
                                                  const float* __restrict__ cell,
                                                  const float* __restrict__ M,
                                                  float* __restrict__ out) {
    int b = blockIdx.x;
    int tid = threadIdx.x;
    int wave = tid >> 6;
    int lane = tid & 63;
    int grp = lane >> 4;   // 4 row-groups per wave
    int l16 = lane & 15;   // 16 lanes per row

    __shared__ float sc[NROW];
    __shared__ float sm[NROW];
    __shared__ float red[4];
    __shared__ float wp[4][F];  // per-wave partial of w
    __shared__ float wsh[F];    // reduced w

    const float* crow = cell + (size_t)b * F;

    // ---- Phase 1: w = cell[b] @ M ----
    {
        int c = lane;        // col quad index (cols 4c..4c+3)
        int fp = wave;       // f partition
        vf4 acc = {0.f, 0.f, 0.f, 0.f};
        const float* Mp = M + (size_t)(fp * 64) * F + 4 * c;
        const float* cp = crow + fp * 64;
#pragma unroll 8
        for (int f = 0; f < 64; f++) {
            vf4 m4 = *(const vf4*)(Mp + (size_t)f * F);
            float cf = cp[f];  // block+wave uniform -> s_load
            acc.x += cf * m4.x;
            acc.y += cf * m4.y;
            acc.z += cf * m4.z;
            acc.w += cf * m4.w;
        }
        *(vf4*)&wp[fp][4 * c] = acc;
    }
    __syncthreads();
    wsh[tid] = wp[0][tid] + wp[1][tid] + wp[2][tid] + wp[3][tid];

    // cell fragments + ||cell|| (no LDS dependence, overlaps)
    vf4 c4[4];
    float cs = 0.f;
#pragma unroll
    for (int j = 0; j < 4; j++) {
        c4[j] = *(const vf4*)&crow[j * 64 + l16 * 4];
        cs += c4[j].x * c4[j].x + c4[j].y * c4[j].y + c4[j].z * c4[j].z + c4[j].w * c4[j].w;
    }
#pragma unroll
    for (int m = 1; m < 16; m <<= 1) cs += __shfl_xor(cs, m, 64);
    float invc = 1.0f / fmaxf(sqrtf(cs), EPS);
    __syncthreads();

    // w fragments from LDS
    vf4 w4[4];
#pragma unroll
    for (int j = 0; j < 4; j++) w4[j] = *(const vf4*)&wsh[j * 64 + l16 * 4];

    const float* dbase = drug + (size_t)b * NROW * F;
    // ---- Phase 2: each wave handles 32 rows: 8 iterations x 4 groups ----
#pragma unroll 2
    for (int it = 0; it < 8; it++) {
        int n = wave * 32 + it * 4 + grp;
        const float* drow = dbase + (size_t)n * F;
        float an = 0.f, aw = 0.f, ac = 0.f;
#pragma unroll
        for (int j = 0; j < 4; j++) {
            vf4 v = __builtin_nontemporal_load((const vf4*)&drow[j * 64 + l16 * 4]);
            an += v.x * v.x + v.y * v.y + v.z * v.z + v.w * v.w;
            aw += v.x * w4[j].x + v.y * w4[j].y + v.z * w4[j].z + v.w * w4[j].w;
            ac += v.x * c4[j].x + v.y * c4[j].y + v.z * c4[j].z + v.w * c4[j].w;
        }
#pragma unroll
        for (int m = 1; m < 16; m <<= 1) {
            an += __shfl_xor(an, m, 64);
            aw += __shfl_xor(aw, m, 64);
            ac += __shfl_xor(ac, m, 64);
        }
        if (l16 == 0) {
            float inv = invc / fmaxf(sqrtf(an), EPS);
            sc[n] = aw * inv;
            sm[n] = ac * inv;
        }
    }
    __syncthreads();

    // block softmax over 128 scores (threads >=128 duplicate for max, zero for sum)
    float s = sc[tid & 127];
    float v = s;
#pragma unroll
    for (int m = 1; m < 64; m <<= 1) v = fmaxf(v, __shfl_xor(v, m, 64));
    if (lane == 0) red[wave] = v;
    __syncthreads();
    float gmax = fmaxf(fmaxf(red[0], red[1]), fmaxf(red[2], red[3]));
    float e = expf(s - gmax);
    float t = (tid < NROW) ? e : 0.f;
#pragma unroll
    for (int m = 1; m < 64; m <<= 1) t += __shfl_xor(t, m, 64);
    __syncthreads();
    if (lane == 0) red[wave] = t;
    __syncthreads();
    float tot = red[0] + red[1] + red[2] + red[3];
    if (tid < NROW) {
        out[(size_t)b * NROW + tid] = (e / tot) * sm[tid & 127];
    }
}

extern "C" void kernel_launch(void* const* d_in, const int* in_sizes, int n_in,
                              void* d_out, int out_size, void* d_ws, size_t ws_size,
                              hipStream_t stream) {
    const float* drug = (const float*)d_in[0];  // [B, N, F]
    const float* cell = (const float*)d_in[1];  // [B, F]
    const float* k = (const float*)d_in[2];     // [F, F]
    const float* q = (const float*)d_in[3];     // [F, F]
    float* out = (float*)d_out;                 // [B, N]

    int B = in_sizes[1] / F;  // 2048

    float* M = (float*)d_ws;  // F*F

    // K1: M = q @ k^T
    qkT_kernel<<<dim3(F), dim3(256), 0, stream>>>(q, k, M);
    // K3: fused w-gemv + norms/scores/softmax/output
    fused_main<<<dim3(B), dim3(256), 0, stream>>>(drug, cell, M, out);
}

// Round 5
// 358.209 us; speedup vs baseline: 1.0723x; 1.0134x over previous
//
#include <hip/hip_runtime.h>
#include <math.h>

#define F 256
#define NROW 128
#define BPB 4      // batches per block
#define EPS 1e-12f

typedef float vf4 __attribute__((ext_vector_type(4)));

// ---------------- K1: M[f,g] = q_row_f . k_row_g  (M = q @ k^T) ----------------
__global__ __launch_bounds__(256) void qkT_kernel(const float* __restrict__ q,
                                                  const float* __restrict__ k,
                                                  float* __restrict__ M) {
    __shared__ float qs[F];
    int f = blockIdx.x;
    qs[threadIdx.x] = q[(size_t)f * F + threadIdx.x];
    __syncthreads();
    int g = threadIdx.x;
    const float4* kr = (const float4*)(k + (size_t)g * F);
    const float4* qr = (const float4*)qs;
    float acc = 0.f;
#pragma unroll 8
    for (int j = 0; j < F / 4; j++) {
        float4 kv = kr[j];
        float4 qv = qr[j];
        acc += kv.x * qv.x + kv.y * qv.y + kv.z * qv.z + kv.w * qv.w;
    }
    M[(size_t)f * F + g] = acc;
}

// ---------------- K3: fused main, BPB batches per block ----------------
// Phase 1: w[b0+bi] = cell[b0+bi] @ M for bi=0..3, reading each M row ONCE
//   (M is L2-resident; aggregate M traffic = 512 blocks*256KB = 128 MB).
//   Wave fp covers f in [fp*64,fp*64+64); lane covers cols 4*lane..+3.
//   cell[b][f] is block-uniform -> scalar loads. Partials reduced via LDS.
//   Wave bi also computes 1/||cell[b0+bi]|| via 64-lane butterfly.
// Phase 2: per batch bi, per row n: an=|d|^2, aw=w.d, ac=cell.d;
//   score=aw*invc/|d|, sim=ac*invc/|d|. Drug streamed nontemporal.
// Epilogue: wave w owns batch w's 128-wide softmax fully in-wave.
__global__ __launch_bounds__(256) void fused_main(const float* __restrict__ drug,
                                                  const float* __restrict__ cell,
                                                  const float* __restrict__ M,
                                                  float* __restrict__ out) {
    int b0 = blockIdx.x * BPB;
    int tid = threadIdx.x;
    int wave = tid >> 6;
    int lane = tid & 63;
    int grp = lane >> 4;   // 4 row-groups per wave
    int l16 = lane & 15;   // 16 lanes per row

    __shared__ float wp[4][BPB][F];   // per-wave partials of w   (16 KB)
    __shared__ float wsh[BPB][F];     // reduced w                ( 4 KB)
    __shared__ float sc[BPB][NROW];   // scores                   ( 2 KB)
    __shared__ float sm[BPB][NROW];   // sims                     ( 2 KB)
    __shared__ float invc_sh[BPB];

    // ---- Phase 1: w = cell @ M, shared M reads across BPB batches ----
    {
        const float* Mp = M + (size_t)(wave * 64) * F + 4 * lane;
        const float* cp = cell + (size_t)b0 * F + wave * 64;
        vf4 acc[BPB];
#pragma unroll
        for (int bi = 0; bi < BPB; bi++) acc[bi] = (vf4){0.f, 0.f, 0.f, 0.f};
#pragma unroll 8
        for (int f = 0; f < 64; f++) {
            vf4 m4 = *(const vf4*)(Mp + (size_t)f * F);
#pragma unroll
            for (int bi = 0; bi < BPB; bi++) {
                float cf = cp[(size_t)bi * F + f];  // uniform -> s_load
                acc[bi].x += cf * m4.x;
                acc[bi].y += cf * m4.y;
                acc[bi].z += cf * m4.z;
                acc[bi].w += cf * m4.w;
            }
        }
#pragma unroll
        for (int bi = 0; bi < BPB; bi++) *(vf4*)&wp[wave][bi][4 * lane] = acc[bi];
    }
    // wave `wave` computes ||cell[b0+wave]||
    {
        vf4 cv = *(const vf4*)&cell[(size_t)(b0 + wave) * F + 4 * lane];
        float cs = cv.x * cv.x + cv.y * cv.y + cv.z * cv.z + cv.w * cv.w;
#pragma unroll
        for (int m = 1; m < 64; m <<= 1) cs += __shfl_xor(cs, m, 64);
        if (lane == 0) invc_sh[wave] = 1.0f / fmaxf(sqrtf(cs), EPS);
    }
    __syncthreads();
#pragma unroll
    for (int bi = 0; bi < BPB; bi++) {
        wsh[bi][tid] = wp[0][bi][tid] + wp[1][bi][tid] + wp[2][bi][tid] + wp[3][bi][tid];
    }
    __syncthreads();

    // ---- Phase 2: stream drug for BPB batches ----
#pragma unroll
    for (int bi = 0; bi < BPB; bi++) {
        int b = b0 + bi;
        vf4 w4[4], c4[4];
#pragma unroll
        for (int j = 0; j < 4; j++) {
            w4[j] = *(const vf4*)&wsh[bi][j * 64 + l16 * 4];
            c4[j] = *(const vf4*)&cell[(size_t)b * F + j * 64 + l16 * 4];
        }
        float invc = invc_sh[bi];
        const float* dbase = drug + (size_t)b * NROW * F;
#pragma unroll 2
        for (int it = 0; it < 8; it++) {
            int n = wave * 32 + it * 4 + grp;
            const float* drow = dbase + (size_t)n * F;
            float an = 0.f, aw = 0.f, ac = 0.f;
#pragma unroll
            for (int j = 0; j < 4; j++) {
                vf4 v = __builtin_nontemporal_load((const vf4*)&drow[j * 64 + l16 * 4]);
                an += v.x * v.x + v.y * v.y + v.z * v.z + v.w * v.w;
                aw += v.x * w4[j].x + v.y * w4[j].y + v.z * w4[j].z + v.w * w4[j].w;
                ac += v.x * c4[j].x + v.y * c4[j].y + v.z * c4[j].z + v.w * c4[j].w;
            }
#pragma unroll
            for (int m = 1; m < 16; m <<= 1) {
                an += __shfl_xor(an, m, 64);
                aw += __shfl_xor(aw, m, 64);
                ac += __shfl_xor(ac, m, 64);
            }
            if (l16 == 0) {
                float inv = invc / fmaxf(sqrtf(an), EPS);
                sc[bi][n] = aw * inv;
                sm[bi][n] = ac * inv;
            }
        }
    }
    __syncthreads();

    // ---- Epilogue: wave w handles batch b0+w's softmax, fully in-wave ----
    {
        int bi = wave;
        float s0 = sc[bi][lane];
        float s1 = sc[bi][lane + 64];
        float mx = fmaxf(s0, s1);
#pragma unroll
        for (int m = 1; m < 64; m <<= 1) mx = fmaxf(mx, __shfl_xor(mx, m, 64));
        float e0 = expf(s0 - mx);
        float e1 = expf(s1 - mx);
        float t = e0 + e1;
#pragma unroll
        for (int m = 1; m < 64; m <<= 1) t += __shfl_xor(t, m, 64);
        float rt = 1.0f / t;
        float* orow = out + (size_t)(b0 + bi) * NROW;
        orow[lane] = e0 * rt * sm[bi][lane];
        orow[lane + 64] = e1 * rt * sm[bi][lane + 64];
    }
}

extern "C" void kernel_launch(void* const* d_in, const int* in_sizes, int n_in,
                              void* d_out, int out_size, void* d_ws, size_t ws_size,
                              hipStream_t stream) {
    const float* drug = (const float*)d_in[0];  // [B, N, F]
    const float* cell = (const float*)d_in[1];  // [B, F]
    const float* k = (const float*)d_in[2];     // [F, F]
    const float* q = (const float*)d_in[3];     // [F, F]
    float* out = (float*)d_out;                 // [B, N]

    int B = in_sizes[1] / F;  // 2048

    float* M = (float*)d_ws;  // F*F

    // K1: M = q @ k^T
    qkT_kernel<<<dim3(F), dim3(256), 0, stream>>>(q, k, M);
    // K3: fused w-gemv (BPB batches/block) + norms/scores/softmax/output
    fused_main<<<dim3(B / BPB), dim3(256), 0, stream>>>(drug, cell, M, out);
}